// Round 10
// baseline (102.023 us; speedup 1.0000x reference)
//
#include <hip/hip_runtime.h>
#include <hip/hip_bf16.h>
#include <cstdint>
#include <cstddef>

#define BATCH 16
#define NROWS 4096
#define MROWS 2048
#define DDIM  256
#define NSPLIT 2
#define NCHUNKS 8            // (NROWS/NSPLIT)/256

typedef __attribute__((ext_vector_type(8))) short short8;
typedef __attribute__((ext_vector_type(4))) float f32x4;

static __device__ __forceinline__ unsigned short f2bf(float f) {
  unsigned int x = __float_as_uint(f);
  x += 0x7fffu + ((x >> 16) & 1u);
  return (unsigned short)(x >> 16);
}

// ---------------- Kernel 1: row L2-normalize + bf16 cast ----------------
__global__ void __launch_bounds__(256) norm_cast(
    const float* __restrict__ x1, const float* __restrict__ x2,
    unsigned short* __restrict__ aout, unsigned short* __restrict__ bout,
    unsigned* __restrict__ counter) {
  if (blockIdx.x == 0 && threadIdx.x == 0) *counter = 0u;  // for loss kernel
  const int wid  = threadIdx.x >> 6;
  const int lane = threadIdx.x & 63;
  const long long row = (long long)blockIdx.x * 4 + wid;
  const long long R1 = (long long)BATCH * NROWS;
  const long long R2 = (long long)BATCH * MROWS;
  if (row >= R1 + R2) return;
  const float* src; unsigned short* dst;
  if (row < R1) { src = x1 + row * DDIM; dst = aout + row * DDIM; }
  else { long long r2 = row - R1; src = x2 + r2 * DDIM; dst = bout + r2 * DDIM; }
  float4 v = ((const float4*)src)[lane];
  float ss = v.x*v.x + v.y*v.y + v.z*v.z + v.w*v.w;
  #pragma unroll
  for (int o = 32; o >= 1; o >>= 1) ss += __shfl_xor(ss, o, 64);
  float n = sqrtf(ss);
  float sc = 1.0f / fmaxf(n, 1e-12f);
  ushort4 o;
  o.x = f2bf(v.x * sc); o.y = f2bf(v.y * sc);
  o.z = f2bf(v.z * sc); o.w = f2bf(v.w * sc);
  ((ushort4*)dst)[lane] = o;
}

// ---------------- Kernel 2: merged-phase 256x256 fused GEMM + column-max ----------------
typedef __attribute__((address_space(1))) const void gas_t;
typedef __attribute__((address_space(3))) void las_t;
#define GLL16(g, l) __builtin_amdgcn_global_load_lds((gas_t*)(g), (las_t*)(l), 16, 0, 0)

// LDS slots: [256 rows][32 k] bf16 = 16 KB each. A: parity x ks, then B.
#define LDSA(P,K) (lds + (((P)*2+(K))<<14))
#define LDSB(P,K) (lds + 65536 + (((P)*2+(K))<<14))

static __device__ __forceinline__ short8 ldsfrag(const char* slot, int row, int pslot) {
  return *(const short8*)(slot + row * 64 + (pslot << 4));
}

__global__ void __launch_bounds__(512, 1) maxsim_gemm8(
    const unsigned short* __restrict__ A,   // [BATCH][NROWS][DDIM]
    const unsigned short* __restrict__ Bm,  // [BATCH][MROWS][DDIM]
    float* __restrict__ partials)           // [NSPLIT][BATCH][MROWS]
{
  __shared__ __align__(16) char lds[131072];

  const int t = threadIdx.x;
  const int lane = t & 63;
  const int w = t >> 6;
  const int wr = w >> 2;     // n-half (wave owns 128 rows)
  const int wc = w & 3;      // m-quarter (wave owns 64 cols)
  const int lrow = lane & 15;
  const int pslot = (lane >> 4) ^ ((lane >> 1) & 3);  // swizzled 16B slot for frag reads

  // XCD-aware bijective swizzle: 256 blocks, XCD k owns batches {2k,2k+1}.
  const int hw = blockIdx.x;
  const int logical = (hw & 7) * 32 + (hw >> 3);
  const int mt = logical & 7;
  const int grp = logical >> 3;
  const int sp = grp & 1;
  const int bb = grp >> 1;

  const int m0 = mt * 256;
  const int nbase = sp * (NROWS / NSPLIT);

  const unsigned short* Aba = A  + (size_t)bb * NROWS * DDIM;
  const unsigned short* Bba = Bm + ((size_t)bb * MROWS + m0) * DDIM;

  // Per-thread staging bases: chunk c = w*2+i covers rows c*16..+15.
  // Source k-slot pre-swizzled: sphys = (lane&3) ^ ((lane>>3)&3).
  const int r0 = (w * 2 + 0) * 16 + (lane >> 2);
  const int r1 = (w * 2 + 1) * 16 + (lane >> 2);
  const int sph8 = (((lane & 3) ^ ((lane >> 3) & 3)) << 3);
  const unsigned short* sA0 = Aba + (size_t)r0 * DDIM + sph8;
  const unsigned short* sA1 = Aba + (size_t)r1 * DDIM + sph8;
  const unsigned short* sB0 = Bba + (size_t)r0 * DDIM + sph8;
  const unsigned short* sB1 = Bba + (size_t)r1 * DDIM + sph8;
  const int l0 = (w * 2 + 0) * 1024 + lane * 16;   // slot-relative LDS dest
  const int l1 = (w * 2 + 1) * 1024 + lane * 16;

  #define STAGE_A(SLOT, OFF) do { \
    GLL16(sA0 + (OFF), (SLOT) + l0); GLL16(sA1 + (OFF), (SLOT) + l1); } while (0)
  #define STAGE_B(SLOT, OFF) do { \
    GLL16(sB0 + (OFF), (SLOT) + l0); GLL16(sB1 + (OFF), (SLOT) + l1); } while (0)

  f32x4 acc[8][4] = {};
  short8 afr[8], bfr[4];
  float cm[4] = {-INFINITY, -INFINITY, -INFINITY, -INFINITY};

  // ---- Prologue: tile0 (4 halves) + tile1's {B ks0, A ks0, B ks1}.
  STAGE_A(LDSA(0,0), nbase * DDIM + 0);
  STAGE_B(LDSB(0,0), 0);
  STAGE_A(LDSA(0,1), nbase * DDIM + 32);
  STAGE_B(LDSB(0,1), 32);
  STAGE_B(LDSB(1,0), 64);
  STAGE_A(LDSA(1,0), nbase * DDIM + 64);
  STAGE_B(LDSB(1,1), 96);
  asm volatile("s_waitcnt vmcnt(6)" ::: "memory");   // tile0 fully landed
  __builtin_amdgcn_s_barrier();

  // Merged phase: 12 ds_reads (B4 + A8) + 2 stage units + BAR + 32 MFMA + BAR.
  // No manual lgkm wait: reads are compiler-visible, so hipcc inserts
  // progressive lgkmcnt(8/4/0) inside the MFMA cluster (late reads drain
  // under early MFMAs).
  #define PHASE2(PAR, KS, STAGE1, STAGE2, VMW) do {                                \
    _Pragma("unroll")                                                              \
    for (int nj = 0; nj < 4; ++nj)                                                 \
      bfr[nj] = ldsfrag(LDSB(PAR,KS), wc*64 + nj*16 + lrow, pslot);                \
    _Pragma("unroll")                                                              \
    for (int mi = 0; mi < 8; ++mi)                                                 \
      afr[mi] = ldsfrag(LDSA(PAR,KS), wr*128 + mi*16 + lrow, pslot);               \
    STAGE1;                                                                        \
    STAGE2;                                                                        \
    __builtin_amdgcn_s_barrier();                                                  \
    __builtin_amdgcn_s_setprio(1);                                                 \
    _Pragma("unroll")                                                              \
    for (int mi = 0; mi < 8; ++mi)                                                 \
      _Pragma("unroll")                                                            \
      for (int nj = 0; nj < 4; ++nj)                                               \
        acc[mi][nj] = __builtin_amdgcn_mfma_f32_16x16x32_bf16(                     \
            afr[mi], bfr[nj], acc[mi][nj], 0, 0, 0);                               \
    __builtin_amdgcn_s_setprio(0);                                                 \
    if (VMW) asm volatile("s_waitcnt vmcnt(6)" ::: "memory");                      \
    __builtin_amdgcn_s_barrier();                                                  \
  } while (0)

  for (int nc = 0; nc < NCHUNKS; ++nc) {
    #pragma unroll
    for (int kt = 0; kt < 4; ++kt) {
      const int par  = kt & 1;
      const int npar = par ^ 1;
      const int T = nc * 4 + kt;
      // Stage ledger (same content as 8-phase version, 2 issue points):
      // ph0: {A-T+1 ks1, B-T+2 ks0}; ph1: {A-T+2 ks0, B-T+2 ks1}.
      // vmcnt(6) at ph1 drains exactly tile T+1's four halves.
      const int ncA1 = (kt < 3) ? nc : ((nc + 1) & (NCHUNKS - 1));  // T+1's chunk
      const int kA1  = ((kt + 1) & 3) * 64 + 32;
      const int ncT2 = (kt < 2) ? nc : ((nc + 1) & (NCHUNKS - 1));  // T+2 (junk-wrap @T=30)
      const int kT2  = ((kt + 2) & 3) * 64;
      const int offA1 = (nbase + ncA1 * 256) * DDIM + kA1;
      const int offA2 = (nbase + ncT2 * 256) * DDIM + kT2;
      const bool wg = T < 31;   // no stages in the last tile

      PHASE2(par, 0,
             if (wg) STAGE_A(LDSA(npar,1), offA1),
             if (wg) STAGE_B(LDSB(par,0), kT2), 0);
      PHASE2(par, 1,
             if (wg) STAGE_A(LDSA(par,0), offA2),
             if (wg) STAGE_B(LDSB(par,1), kT2 + 32), 1);
    }
    // fold this n-chunk's C tile into running column max (max3-fusable chain)
    #pragma unroll
    for (int nj = 0; nj < 4; ++nj) {
      float v = cm[nj];
      #pragma unroll
      for (int mi = 0; mi < 8; ++mi) {
        v = fmaxf(fmaxf(fmaxf(fmaxf(v, acc[mi][nj][0]), acc[mi][nj][1]),
                        acc[mi][nj][2]), acc[mi][nj][3]);
        acc[mi][nj] = (f32x4){0.0f, 0.0f, 0.0f, 0.0f};
      }
      cm[nj] = v;
    }
  }
  #undef PHASE2

  // ---- Epilogue: drain DMA, reduce max across lanes/waves, write partials
  asm volatile("s_waitcnt vmcnt(0)" ::: "memory");
  __builtin_amdgcn_s_barrier();
  float* cmax = (float*)lds;   // [2][256]
  #pragma unroll
  for (int nj = 0; nj < 4; ++nj) {
    cm[nj] = fmaxf(cm[nj], __shfl_xor(cm[nj], 16, 64));
    cm[nj] = fmaxf(cm[nj], __shfl_xor(cm[nj], 32, 64));
  }
  if (lane < 16) {
    #pragma unroll
    for (int nj = 0; nj < 4; ++nj)
      cmax[wr * 256 + wc * 64 + nj * 16 + lane] = cm[nj];
  }
  __syncthreads();
  if (t < 256) {
    float v = fmaxf(cmax[t], cmax[256 + t]);
    partials[((size_t)sp * BATCH + bb) * MROWS + m0 + t] = v;
  }
}

// ---------------- Kernel 3: per-batch loss + last-block final sum ----------------
__global__ void __launch_bounds__(256) batch_loss_final(
    const float* __restrict__ partials, const float* __restrict__ y,
    float* __restrict__ out, float* __restrict__ bloss,
    unsigned* __restrict__ counter) {
  __shared__ float red[4];
  __shared__ bool amlast;
  const int b = blockIdx.x;
  const int t = threadIdx.x;
  const int lane = t & 63;
  const int w = t >> 6;
  float s = 0.0f;
  for (int m = t; m < MROWS; m += 256) {
    float v = partials[(size_t)b * MROWS + m];
    #pragma unroll
    for (int sp = 1; sp < NSPLIT; ++sp)
      v = fmaxf(v, partials[((size_t)sp * BATCH + b) * MROWS + m]);
    s += v;
  }
  #pragma unroll
  for (int o = 32; o >= 1; o >>= 1) s += __shfl_xor(s, o, 64);
  if (lane == 0) red[w] = s;
  __syncthreads();
  if (t == 0) {
    float sum = red[0] + red[1] + red[2] + red[3];
    float mean = sum / (float)MROWS;
    float d = mean - y[b];
    bloss[b] = d * d;   // Y_SCALE == 1.0
    __threadfence();
    unsigned old = atomicAdd(counter, 1u);
    amlast = (old == BATCH - 1);
  }
  __syncthreads();
  if (amlast && t == 0) {
    __threadfence();
    float tot = 0.0f;
    #pragma unroll
    for (int i = 0; i < BATCH; ++i) tot += bloss[i];
    out[0] = tot;
    *counter = 0;   // reset for next replay (deterministic across calls)
  }
}

extern "C" void kernel_launch(void* const* d_in, const int* in_sizes, int n_in,
                              void* d_out, int out_size, void* d_ws, size_t ws_size,
                              hipStream_t stream) {
  const float* x1 = (const float*)d_in[0];
  const float* x2 = (const float*)d_in[1];
  const float* y  = (const float*)d_in[2];
  float* out = (float*)d_out;

  unsigned short* aBF = (unsigned short*)d_ws;
  unsigned short* bBF = aBF + (size_t)BATCH * NROWS * DDIM;
  float* partials = (float*)(bBF + (size_t)BATCH * MROWS * DDIM);
  float* bloss = partials + (size_t)NSPLIT * BATCH * MROWS;
  unsigned* counter = (unsigned*)(bloss + BATCH);

  const int totRows = BATCH * (NROWS + MROWS);
  norm_cast<<<(totRows + 3) / 4, 256, 0, stream>>>(x1, x2, aBF, bBF, counter);
  maxsim_gemm8<<<BATCH * 8 * NSPLIT, 512, 0, stream>>>(aBF, bBF, partials);
  batch_loss_final<<<BATCH, 256, 0, stream>>>(partials, y, out, bloss, counter);
}

// Round 11
// 85.750 us; speedup vs baseline: 1.1898x; 1.1898x over previous
//
#include <hip/hip_runtime.h>
#include <hip/hip_bf16.h>
#include <cstdint>
#include <cstddef>

#define BATCH 16
#define NROWS 4096
#define MROWS 2048
#define DDIM  256
#define NSPLIT 2
#define NCHUNKS 8            // (NROWS/NSPLIT)/256

typedef __attribute__((ext_vector_type(8))) short short8;
typedef __attribute__((ext_vector_type(4))) float f32x4;

static __device__ __forceinline__ unsigned short f2bf(float f) {
  unsigned int x = __float_as_uint(f);
  x += 0x7fffu + ((x >> 16) & 1u);
  return (unsigned short)(x >> 16);
}

// ---------------- Kernel 1: row L2-normalize + bf16 cast ----------------
__global__ void __launch_bounds__(256) norm_cast(
    const float* __restrict__ x1, const float* __restrict__ x2,
    unsigned short* __restrict__ aout, unsigned short* __restrict__ bout) {
  const int wid  = threadIdx.x >> 6;
  const int lane = threadIdx.x & 63;
  const long long row = (long long)blockIdx.x * 4 + wid;
  const long long R1 = (long long)BATCH * NROWS;
  const long long R2 = (long long)BATCH * MROWS;
  if (row >= R1 + R2) return;
  const float* src; unsigned short* dst;
  if (row < R1) { src = x1 + row * DDIM; dst = aout + row * DDIM; }
  else { long long r2 = row - R1; src = x2 + r2 * DDIM; dst = bout + r2 * DDIM; }
  float4 v = ((const float4*)src)[lane];
  float ss = v.x*v.x + v.y*v.y + v.z*v.z + v.w*v.w;
  #pragma unroll
  for (int o = 32; o >= 1; o >>= 1) ss += __shfl_xor(ss, o, 64);
  float n = sqrtf(ss);
  float sc = 1.0f / fmaxf(n, 1e-12f);
  ushort4 o;
  o.x = f2bf(v.x * sc); o.y = f2bf(v.y * sc);
  o.z = f2bf(v.z * sc); o.w = f2bf(v.w * sc);
  ((ushort4*)dst)[lane] = o;
}

// ---------------- Kernel 2: 8-phase 256x256 fused GEMM + column-max ----------------
typedef __attribute__((address_space(1))) const void gas_t;
typedef __attribute__((address_space(3))) void las_t;
#define GLL16(g, l) __builtin_amdgcn_global_load_lds((gas_t*)(g), (las_t*)(l), 16, 0, 0)

// LDS slots: [256 rows][32 k] bf16 = 16 KB each. A: parity x ks, then B.
#define LDSA(P,K) (lds + (((P)*2+(K))<<14))
#define LDSB(P,K) (lds + 65536 + (((P)*2+(K))<<14))

static __device__ __forceinline__ short8 ldsfrag(const char* slot, int row, int pslot) {
  return *(const short8*)(slot + row * 64 + (pslot << 4));
}

__global__ void __launch_bounds__(512, 1) maxsim_gemm8(
    const unsigned short* __restrict__ A,   // [BATCH][NROWS][DDIM]
    const unsigned short* __restrict__ Bm,  // [BATCH][MROWS][DDIM]
    float* __restrict__ partials)           // [NSPLIT][BATCH][MROWS]
{
  __shared__ __align__(16) char lds[131072];

  const int t = threadIdx.x;
  const int lane = t & 63;
  const int w = t >> 6;
  const int wr = w >> 2;     // n-half (wave owns 128 rows)
  const int wc = w & 3;      // m-quarter (wave owns 64 cols)
  const int lrow = lane & 15;
  const int pslot = (lane >> 4) ^ ((lane >> 1) & 3);  // swizzled 16B slot for frag reads

  // XCD-aware bijective swizzle: 256 blocks, XCD k owns batches {2k,2k+1}.
  const int hw = blockIdx.x;
  const int logical = (hw & 7) * 32 + (hw >> 3);
  const int mt = logical & 7;
  const int grp = logical >> 3;
  const int sp = grp & 1;
  const int bb = grp >> 1;

  const int m0 = mt * 256;
  const int nbase = sp * (NROWS / NSPLIT);

  const unsigned short* Aba = A  + (size_t)bb * NROWS * DDIM;
  const unsigned short* Bba = Bm + ((size_t)bb * MROWS + m0) * DDIM;

  // Per-thread staging bases (hoisted): chunk c = w*2+i covers rows c*16..+15.
  // Source k-slot pre-swizzled: sphys = (lane&3) ^ ((lane>>3)&3).
  const int r0 = (w * 2 + 0) * 16 + (lane >> 2);
  const int r1 = (w * 2 + 1) * 16 + (lane >> 2);
  const int sph8 = (((lane & 3) ^ ((lane >> 3) & 3)) << 3);
  const unsigned short* sA0 = Aba + (size_t)r0 * DDIM + sph8;
  const unsigned short* sA1 = Aba + (size_t)r1 * DDIM + sph8;
  const unsigned short* sB0 = Bba + (size_t)r0 * DDIM + sph8;
  const unsigned short* sB1 = Bba + (size_t)r1 * DDIM + sph8;
  const int l0 = (w * 2 + 0) * 1024 + lane * 16;   // slot-relative LDS dest
  const int l1 = (w * 2 + 1) * 1024 + lane * 16;

  #define STAGE_A(SLOT, OFF) do { \
    GLL16(sA0 + (OFF), (SLOT) + l0); GLL16(sA1 + (OFF), (SLOT) + l1); } while (0)
  #define STAGE_B(SLOT, OFF) do { \
    GLL16(sB0 + (OFF), (SLOT) + l0); GLL16(sB1 + (OFF), (SLOT) + l1); } while (0)

  f32x4 acc[8][4] = {};
  short8 afr[4], bfr[4];
  float cm[4] = {-INFINITY, -INFINITY, -INFINITY, -INFINITY};

  // ---- Prologue: tile0 (4 halves) + tile1's {B ks0, A ks0, B ks1}.
  STAGE_A(LDSA(0,0), nbase * DDIM + 0);
  STAGE_B(LDSB(0,0), 0);
  STAGE_A(LDSA(0,1), nbase * DDIM + 32);
  STAGE_B(LDSB(0,1), 32);
  STAGE_B(LDSB(1,0), 64);
  STAGE_A(LDSA(1,0), nbase * DDIM + 64);
  STAGE_B(LDSB(1,1), 96);
  asm volatile("s_waitcnt vmcnt(6)" ::: "memory");   // tile0 fully landed
  asm volatile("s_barrier" ::: "memory");

  // Phase: [optional B-read] + 4 A-reads; stage 1 half; barrier; 16 MFMA; barrier.
  // No setprio: m190 measured setprio as slightly NEGATIVE on lockstep-barrier
  // GEMMs (needs wave role-split to pay; our 8 waves are convoyed).
  #define PHASE(RDB, BSLOT, ASLOT, MIOFF, STAGE_STMT, VMW) do {                    \
    if (RDB) {                                                                     \
      _Pragma("unroll")                                                            \
      for (int nj = 0; nj < 4; ++nj)                                               \
        bfr[nj] = ldsfrag(BSLOT, wc*64 + nj*16 + lrow, pslot);                     \
    }                                                                              \
    _Pragma("unroll")                                                              \
    for (int mi = 0; mi < 4; ++mi)                                                 \
      afr[mi] = ldsfrag(ASLOT, wr*128 + ((MIOFF)+mi)*16 + lrow, pslot);            \
    STAGE_STMT;                                                                    \
    asm volatile("s_waitcnt lgkmcnt(0)" ::: "memory");                             \
    asm volatile("s_barrier" ::: "memory");                                        \
    _Pragma("unroll")                                                              \
    for (int mi = 0; mi < 4; ++mi)                                                 \
      _Pragma("unroll")                                                            \
      for (int nj = 0; nj < 4; ++nj)                                               \
        acc[(MIOFF)+mi][nj] = __builtin_amdgcn_mfma_f32_16x16x32_bf16(             \
            afr[mi], bfr[nj], acc[(MIOFF)+mi][nj], 0, 0, 0);                       \
    if (VMW) asm volatile("s_waitcnt vmcnt(6)" ::: "memory");                      \
    asm volatile("s_barrier" ::: "memory");                                        \
  } while (0)

  for (int nc = 0; nc < NCHUNKS; ++nc) {
    #pragma unroll
    for (int kt = 0; kt < 4; ++kt) {
      const int par  = kt & 1;
      const int npar = par ^ 1;
      // Stage ledger: ph0 completes tile T+1 (A ks1); ph1-3 issue tile T+2's
      // {B ks0, A ks0, B ks1}. vmcnt(6) at ph3 => tile T+1 fully landed.
      const int ncA1 = (kt < 3) ? nc : ((nc + 1) & (NCHUNKS - 1));  // T+1's chunk
      const int kA1  = ((kt + 1) & 3) * 64 + 32;
      const int ncT2 = (kt < 2) ? nc : ((nc + 1) & (NCHUNKS - 1));  // T+2's chunk
      const int kT2  = ((kt + 2) & 3) * 64;
      const int offA1 = (nbase + ncA1 * 256) * DDIM + kA1;
      const int offA2 = (nbase + ncT2 * 256) * DDIM + kT2;

      PHASE(1, LDSB(par,0), LDSA(par,0), 0, STAGE_A(LDSA(npar,1), offA1), 0);
      PHASE(0, LDSB(par,0), LDSA(par,0), 4, STAGE_B(LDSB(par,0), kT2),    0);
      PHASE(1, LDSB(par,1), LDSA(par,1), 0, STAGE_A(LDSA(par,0), offA2),  0);
      PHASE(0, LDSB(par,1), LDSA(par,1), 4, STAGE_B(LDSB(par,1), kT2+32), 1);
    }
    // fold this n-chunk's C tile into running column max; reset acc
    #pragma unroll
    for (int nj = 0; nj < 4; ++nj) {
      float v = cm[nj];
      #pragma unroll
      for (int mi = 0; mi < 8; ++mi) {
        v = fmaxf(fmaxf(fmaxf(fmaxf(v, acc[mi][nj][0]), acc[mi][nj][1]),
                        acc[mi][nj][2]), acc[mi][nj][3]);
        acc[mi][nj] = (f32x4){0.0f, 0.0f, 0.0f, 0.0f};
      }
      cm[nj] = v;
    }
  }
  #undef PHASE

  // ---- Epilogue: drain DMA, reduce max across lanes/waves, write partials
  asm volatile("s_waitcnt vmcnt(0)" ::: "memory");
  asm volatile("s_barrier" ::: "memory");
  float* cmax = (float*)lds;   // [2][256]
  #pragma unroll
  for (int nj = 0; nj < 4; ++nj) {
    cm[nj] = fmaxf(cm[nj], __shfl_xor(cm[nj], 16, 64));
    cm[nj] = fmaxf(cm[nj], __shfl_xor(cm[nj], 32, 64));
  }
  if (lane < 16) {
    #pragma unroll
    for (int nj = 0; nj < 4; ++nj)
      cmax[wr * 256 + wc * 64 + nj * 16 + lane] = cm[nj];
  }
  __syncthreads();
  if (t < 256) {
    float v = fmaxf(cmax[t], cmax[256 + t]);
    partials[((size_t)sp * BATCH + bb) * MROWS + m0 + t] = v;
  }
}

// ---------------- Kernel 3a: per-batch loss ----------------
__global__ void __launch_bounds__(256) batch_loss(
    const float* __restrict__ partials, const float* __restrict__ y,
    float* __restrict__ bloss) {
  __shared__ float red[4];
  const int b = blockIdx.x;
  const int t = threadIdx.x;
  const int lane = t & 63;
  const int w = t >> 6;
  float s = 0.0f;
  for (int m = t; m < MROWS; m += 256) {
    float v = partials[(size_t)b * MROWS + m];
    #pragma unroll
    for (int sp = 1; sp < NSPLIT; ++sp)
      v = fmaxf(v, partials[((size_t)sp * BATCH + b) * MROWS + m]);
    s += v;
  }
  #pragma unroll
  for (int o = 32; o >= 1; o >>= 1) s += __shfl_xor(s, o, 64);
  if (lane == 0) red[w] = s;
  __syncthreads();
  if (t == 0) {
    float sum = red[0] + red[1] + red[2] + red[3];
    float mean = sum / (float)MROWS;
    float yb = y[b];
    float d = mean - yb;
    bloss[b] = d * d;   // Y_SCALE == 1.0
  }
}

// ---------------- Kernel 3b: combine per-batch losses ----------------
__global__ void __launch_bounds__(64) final_sum(
    const float* __restrict__ bloss, float* __restrict__ out) {
  const int t = threadIdx.x;
  float v = (t < BATCH) ? bloss[t] : 0.0f;
  #pragma unroll
  for (int o = 32; o >= 1; o >>= 1) v += __shfl_xor(v, o, 64);
  if (t == 0) out[0] = v;
}

extern "C" void kernel_launch(void* const* d_in, const int* in_sizes, int n_in,
                              void* d_out, int out_size, void* d_ws, size_t ws_size,
                              hipStream_t stream) {
  const float* x1 = (const float*)d_in[0];
  const float* x2 = (const float*)d_in[1];
  const float* y  = (const float*)d_in[2];
  float* out = (float*)d_out;

  unsigned short* aBF = (unsigned short*)d_ws;
  unsigned short* bBF = aBF + (size_t)BATCH * NROWS * DDIM;
  float* partials = (float*)(bBF + (size_t)BATCH * MROWS * DDIM);
  float* bloss = partials + (size_t)NSPLIT * BATCH * MROWS;

  const int totRows = BATCH * (NROWS + MROWS);
  norm_cast<<<(totRows + 3) / 4, 256, 0, stream>>>(x1, x2, aBF, bBF);
  maxsim_gemm8<<<BATCH * 8 * NSPLIT, 512, 0, stream>>>(aBF, bBF, partials);
  batch_loss<<<BATCH, 256, 0, stream>>>(partials, y, bloss);
  final_sum<<<1, 64, 0, stream>>>(bloss, out);
}